// Round 4
// baseline (1246.449 us; speedup 1.0000x reference)
//
#include <hip/hip_runtime.h>
#include <hip/hip_cooperative_groups.h>
#include <math.h>

namespace cg = cooperative_groups;

// GLIFR (BNNFC) : B=32, T=1000, IN=256, H=512, OUT=128, A=2, DELAY=20
//  ph1: SYN[t][b][h] = input @ W_iv                      (fp32 tiled GEMM)
//  cvt: Wt[h][k] = bf16(W_lat[k][h])                     (transpose+convert)
//  ph2: ONE persistent cooperative kernel: 50 stages, grid.sync() between.
//       Per block: W_lat slice resident in LDS, state in registers.
//  ph3: out = F @ out_w + out_b                          (bf16-A tiled GEMM)

constexpr int Bsz   = 32;
constexpr int Tn    = 1000;
constexpr int INn   = 256;
constexpr int Hn    = 512;
constexpr int OUTn  = 128;
constexpr int DELAY = 20;
constexpr int NBLK  = Tn / DELAY;   // 50
constexpr float DTc = 0.05f;
constexpr float Rc  = 0.1f;
constexpr int BH = Bsz * Hn;                  // 16384
constexpr long STG = (long)Bsz * DELAY * Hn;  // 327680 elems per F stage

typedef __attribute__((ext_vector_type(8))) short short8v;  // 8 bf16
typedef __attribute__((ext_vector_type(4))) float f32x4;

__device__ __forceinline__ float sigmoidf_(float x) {
    return 1.0f / (1.0f + expf(-x));
}
__device__ __forceinline__ float bf2f(unsigned short u) {
    return __uint_as_float(((unsigned)u) << 16);
}
__device__ __forceinline__ unsigned short f2bf(float f) {
    unsigned x = __float_as_uint(f);
    return (unsigned short)((x + 0x7fff + ((x >> 16) & 1)) >> 16);  // RNE
}

// ---------------------------------------------------------------------------
// fp32 tiled GEMM (phase 1): 64x64 tile, BK=16, 256 thr, 4x4 micro.
// A row m=(t*32+b) maps to input[(b*Tn + t)*K]  (input is [B,T,IN])
// ---------------------------------------------------------------------------
__global__ __launch_bounds__(256) void gemm_ff(
    const float* __restrict__ A, const float* __restrict__ B,
    float* __restrict__ C, int M, int N, int K)
{
    constexpr int BK = 16;
    __shared__ float As[BK][64 + 4];
    __shared__ float Bs[BK][64];

    const int tid = threadIdx.x;
    const int m0 = blockIdx.x * 64;
    const int n0 = blockIdx.y * 64;

    const int la_m  = tid >> 2;
    const int la_kq = (tid & 3) * 4;
    const int m = m0 + la_m;
    const long arow = ((long)(m & 31) * Tn + (m >> 5)) * (long)K;
    const int lb_k = tid >> 4;
    const int lb_n = (tid & 15) * 4;
    const int ty = tid >> 4, tx = tid & 15;

    float acc[4][4] = {};
    for (int k0 = 0; k0 < K; k0 += BK) {
        float4 av = *(const float4*)&A[arow + k0 + la_kq];
        As[la_kq + 0][la_m] = av.x;
        As[la_kq + 1][la_m] = av.y;
        As[la_kq + 2][la_m] = av.z;
        As[la_kq + 3][la_m] = av.w;
        *(float4*)&Bs[lb_k][lb_n] =
            *(const float4*)&B[(long)(k0 + lb_k) * N + n0 + lb_n];
        __syncthreads();
#pragma unroll
        for (int kk = 0; kk < BK; ++kk) {
            float a[4], b[4];
#pragma unroll
            for (int i = 0; i < 4; ++i) a[i] = As[kk][ty * 4 + i];
#pragma unroll
            for (int j = 0; j < 4; ++j) b[j] = Bs[kk][tx * 4 + j];
#pragma unroll
            for (int i = 0; i < 4; ++i)
#pragma unroll
                for (int j = 0; j < 4; ++j)
                    acc[i][j] = fmaf(a[i], b[j], acc[i][j]);
        }
        __syncthreads();
    }
#pragma unroll
    for (int i = 0; i < 4; ++i) {
        long crow = (long)(m0 + ty * 4 + i) * N;
        *(float4*)&C[crow + n0 + tx * 4] =
            make_float4(acc[i][0], acc[i][1], acc[i][2], acc[i][3]);
    }
}

// ---------------------------------------------------------------------------
// W_lat [512][512] fp32 -> Wt [h][k] bf16 (transposed), 32x32 LDS tiles
// ---------------------------------------------------------------------------
__global__ __launch_bounds__(256) void wlat_cvt(
    const float* __restrict__ W, unsigned short* __restrict__ Wt)
{
    __shared__ float tile[32][33];
    const int tid = threadIdx.x;
    const int bx = blockIdx.x & 15, by = blockIdx.x >> 4;
    const int x = tid & 31, y = tid >> 5;   // 32 x 8
#pragma unroll
    for (int j = 0; j < 4; ++j)
        tile[y + j * 8][x] = W[(long)(by * 32 + y + j * 8) * Hn + bx * 32 + x];
    __syncthreads();
#pragma unroll
    for (int j = 0; j < 4; ++j)
        Wt[(long)(bx * 32 + y + j * 8) * Hn + by * 32 + x] =
            f2bf(tile[x][y + j * 8]);
}

// ---------------------------------------------------------------------------
// Phase 2 persistent cooperative kernel.
// Grid 64 blocks (8 rb x 8 cb), 256 threads (4 waves).
//   Block (rb,cb): output rows b0=rb*4..+3 (80 GEMM rows r'=b_local*20+t),
//   cols h0=cb*64..+63. W_lat slice [h0..h0+63][0..511] resident in LDS.
// Per stage k: lateral MFMA GEMM (80x64, K=512) from F[k-1], fused ew
// recurrence (state in regs), write F[k] bf16, grid.sync().
// ---------------------------------------------------------------------------
__global__ __launch_bounds__(256, 1) void phase2_persist(
    const unsigned short* __restrict__ Wt,   // [512][512] bf16 [h][k]
    const float* __restrict__ SYN,           // [1000][32][512] fp32
    unsigned short* __restrict__ Fbf,        // [50][32][20][512] bf16
    const float* __restrict__ tkm, const float* __restrict__ thr,
    const float* __restrict__ aamp, const float* __restrict__ tascr,
    const float* __restrict__ tkasc)
{
    __shared__ unsigned short Wlds[64 * 512];     // 64 KB, swizzled rows of 1024B
    __shared__ unsigned short Albs[2][80 * 128];  // 2 x 20 KB, swizzled rows 256B
    __shared__ float Sy[80][68];                  // 21.75 KB

    const int tid = threadIdx.x;
    const int rb = blockIdx.x >> 3, cb = blockIdx.x & 7;
    const int b0 = rb * 4, h0 = cb * 64;
    const int lane = tid & 63, w = tid >> 6;

    cg::grid_group grid = cg::this_grid();

    // ---- prologue: load W_lat slice into LDS (once)
#pragma unroll
    for (int j = 0; j < 16; ++j) {
        int c = tid + 256 * j;           // 16B-chunk id 0..4095
        int n = c >> 6, kq = c & 63;
        uint4 v = *(const uint4*)&Wt[(long)(h0 + n) * Hn + kq * 8];
        unsigned off = (unsigned)(n * 1024 + kq * 16);
        off ^= (unsigned)((n & 7) << 4);
        *(uint4*)((char*)Wlds + off) = v;
    }

    // ---- per-thread ew params (computed once)
    const int bl = tid >> 6, hl = tid & 63;
    const int bb = b0 + bl, h = h0 + hl;
    const float dkm  = sigmoidf_(tkm[h]);
    const float th   = thr[h];
    const float amp0 = aamp[h],      amp1 = aamp[Hn + h];
    const float r0   = 1.f - 2.f * sigmoidf_(tascr[h]);
    const float r1   = 1.f - 2.f * sigmoidf_(tascr[Hn + h]);
    const float dka0 = sigmoidf_(tkasc[h]);
    const float dka1 = sigmoidf_(tkasc[Hn + h]);
    const float dkmR = dkm * Rc;
    float volt = 0.f, firing = 0.f, a0 = 0.f, a1 = 0.f;

    __syncthreads();

    uint4 ra[5];
    auto loadA = [&](const unsigned short* Fprev, int kt) {
#pragma unroll
        for (int j = 0; j < 5; ++j) {
            int f = tid + 256 * j, row = f >> 4, kq = f & 15;
            ra[j] = *(const uint4*)&Fprev[(long)(b0 * DELAY + row) * Hn
                                          + kt * 128 + kq * 8];
        }
    };
    auto storeA = [&](int buf) {
#pragma unroll
        for (int j = 0; j < 5; ++j) {
            int f = tid + 256 * j, row = f >> 4, kq = f & 15;
            unsigned off = (unsigned)(row * 256 + kq * 16);
            off ^= (unsigned)((row & 7) << 4);
            *(uint4*)((char*)&Albs[buf][0] + off) = ra[j];
        }
    };

#pragma unroll 1
    for (int k = 0; k < NBLK; ++k) {
        // prefetch this stage's feedforward syn into registers
        float sy[DELAY];
        const float* synk = SYN + (long)k * DELAY * BH;
#pragma unroll
        for (int s = 0; s < DELAY; ++s)
            sy[s] = synk[((long)s * Bsz + bb) * Hn + h];

        if (k > 0) {
            const unsigned short* Fprev = Fbf + (long)(k - 1) * STG;
            f32x4 acc[5] = {};
            loadA(Fprev, 0);
#pragma unroll
            for (int kt = 0; kt < 4; ++kt) {
                storeA(kt & 1);
                __syncthreads();
                if (kt < 3) loadA(Fprev, kt + 1);   // prefetch under MFMA
#pragma unroll
                for (int ks = 0; ks < 4; ++ks) {
                    short8v bfr;
                    {
                        int n = w * 16 + (lane & 15);
                        unsigned off = (unsigned)(n * 1024 + kt * 256
                                                  + ks * 64 + (lane >> 4) * 16);
                        off ^= (unsigned)((n & 7) << 4);
                        bfr = *(const short8v*)((char*)Wlds + off);
                    }
#pragma unroll
                    for (int mt = 0; mt < 5; ++mt) {
                        int row = mt * 16 + (lane & 15);
                        unsigned off = (unsigned)(row * 256 + ks * 64
                                                  + (lane >> 4) * 16);
                        off ^= (unsigned)((row & 7) << 4);
                        short8v afr = *(const short8v*)((char*)&Albs[kt & 1][0] + off);
                        acc[mt] = __builtin_amdgcn_mfma_f32_16x16x32_bf16(
                            afr, bfr, acc[mt], 0, 0, 0);
                    }
                }
            }
            // epilogue: acc -> Sy.  C layout: col=lane&15, row=(lane>>4)*4+reg
#pragma unroll
            for (int mt = 0; mt < 5; ++mt)
#pragma unroll
                for (int r = 0; r < 4; ++r)
                    Sy[mt * 16 + (lane >> 4) * 4 + r][w * 16 + (lane & 15)]
                        = acc[mt][r];
            __syncthreads();
        }

        // ---- elementwise recurrence (20 steps), state in registers
        unsigned short* Fo = Fbf + (long)k * STG;
#pragma unroll
        for (int s = 0; s < DELAY; ++s) {
            float sv = sy[s];
            if (k > 0) sv += Sy[bl * DELAY + s][hl];
            a0 = a0 * (r0 * firing * DTc + (1.f - dka0)) + amp0 * firing * DTc;
            a1 = a1 * (r1 * firing * DTc + (1.f - dka1)) + amp1 * firing * DTc;
            volt = volt * (1.f - dkm - firing) + dkmR * (sv + a0 + a1);
            firing = sigmoidf_(volt - th);
            Fo[((long)bb * DELAY + s) * Hn + h] = f2bf(firing);
        }
        __threadfence();
        grid.sync();
    }
}

// ---------------------------------------------------------------------------
// Phase 3: out[b][t][:] = F @ out_w + out_b, A = bf16 stage-blocked F.
// ---------------------------------------------------------------------------
__global__ __launch_bounds__(256) void gemm_out(
    const unsigned short* __restrict__ Fbf, const float* __restrict__ B,
    float* __restrict__ C, const float* __restrict__ bias, int M, int N, int K)
{
    constexpr int BK = 16;
    __shared__ float As[BK][64 + 4];
    __shared__ float Bs[BK][64];

    const int tid = threadIdx.x;
    const int m0 = blockIdx.x * 64;
    const int n0 = blockIdx.y * 64;

    const int la_m  = tid >> 2;
    const int la_kq = (tid & 3) * 4;
    const int m = m0 + la_m;
    const int t = m >> 5, b = m & 31;
    const int ks = t / DELAY, tl = t - ks * DELAY;
    const unsigned short* arow = Fbf + (((long)ks * Bsz + b) * DELAY + tl) * Hn;

    const int lb_k = tid >> 4;
    const int lb_n = (tid & 15) * 4;
    const int ty = tid >> 4, tx = tid & 15;

    float acc[4][4] = {};
    for (int k0 = 0; k0 < K; k0 += BK) {
        const unsigned short* ap = arow + k0 + la_kq;
        As[la_kq + 0][la_m] = bf2f(ap[0]);
        As[la_kq + 1][la_m] = bf2f(ap[1]);
        As[la_kq + 2][la_m] = bf2f(ap[2]);
        As[la_kq + 3][la_m] = bf2f(ap[3]);
        *(float4*)&Bs[lb_k][lb_n] =
            *(const float4*)&B[(long)(k0 + lb_k) * N + n0 + lb_n];
        __syncthreads();
#pragma unroll
        for (int kk = 0; kk < BK; ++kk) {
            float a[4], bvv[4];
#pragma unroll
            for (int i = 0; i < 4; ++i) a[i] = As[kk][ty * 4 + i];
#pragma unroll
            for (int j = 0; j < 4; ++j) bvv[j] = Bs[kk][tx * 4 + j];
#pragma unroll
            for (int i = 0; i < 4; ++i)
#pragma unroll
                for (int j = 0; j < 4; ++j)
                    acc[i][j] = fmaf(a[i], bvv[j], acc[i][j]);
        }
        __syncthreads();
    }
    float4 bv = *(const float4*)&bias[n0 + tx * 4];
#pragma unroll
    for (int i = 0; i < 4; ++i) {
        int mm = m0 + ty * 4 + i;
        long crow = ((long)(mm & 31) * Tn + (mm >> 5)) * (long)N;  // [B,T,OUT]
        float4 v = make_float4(acc[i][0] + bv.x, acc[i][1] + bv.y,
                               acc[i][2] + bv.z, acc[i][3] + bv.w);
        *(float4*)&C[crow + n0 + tx * 4] = v;
    }
}

extern "C" void kernel_launch(void* const* d_in, const int* in_sizes, int n_in,
                              void* d_out, int out_size, void* d_ws, size_t ws_size,
                              hipStream_t stream) {
    const float* input = (const float*)d_in[0];   // [B,T,IN]
    const float* w_iv  = (const float*)d_in[1];   // [IN,H]
    const float* w_lat = (const float*)d_in[2];   // [H,H]
    const float* thr   = (const float*)d_in[3];   // [1,H]
    const float* tkm   = (const float*)d_in[4];   // [1,H]
    const float* aamp  = (const float*)d_in[5];   // [A,1,H]
    const float* tascr = (const float*)d_in[6];   // [A,1,H]
    const float* tkasc = (const float*)d_in[7];   // [A,1,H]
    const float* outw  = (const float*)d_in[8];   // [H,OUT]
    const float* outb  = (const float*)d_in[9];   // [OUT]
    float* out = (float*)d_out;                   // [B,T,OUT]

    const size_t TBH = (size_t)Tn * BH;           // 16,384,000
    float* SYN            = (float*)d_ws;                 // [T][B][H] fp32
    unsigned short* Fbf   = (unsigned short*)(SYN + TBH); // [50][32][20][512] bf16
    unsigned short* Wt    = Fbf + TBH;                    // [512][512] bf16

    const int MTB = Tn * Bsz;                     // 32000

    // Phase 0: convert + transpose W_lat -> bf16
    wlat_cvt<<<256, 256, 0, stream>>>(w_lat, Wt);

    // Phase 1: feedforward GEMM into SYN (time-major [T][B][H], fp32)
    {
        dim3 g(MTB / 64, Hn / 64);
        gemm_ff<<<g, 256, 0, stream>>>(input, w_iv, SYN, MTB, Hn, INn);
    }

    // Phase 2: one persistent cooperative kernel, 50 stages with grid.sync
    {
        const unsigned short* Wt_c = Wt;
        const float* SYN_c = SYN;
        void* params[] = {
            (void*)&Wt_c, (void*)&SYN_c, (void*)&Fbf,
            (void*)&tkm, (void*)&thr, (void*)&aamp, (void*)&tascr, (void*)&tkasc
        };
        hipLaunchCooperativeKernel((const void*)phase2_persist,
                                   dim3(64), dim3(256), params, 0, stream);
    }

    // Phase 3: output projection, writes [B,T,OUT]
    {
        dim3 g(MTB / 64, OUTn / 64);              // 500 x 2
        gemm_out<<<g, 256, 0, stream>>>(Fbf, outw, out, outb, MTB, OUTn, Hn);
    }
}

// Round 5
// 858.821 us; speedup vs baseline: 1.4513x; 1.4513x over previous
//
#include <hip/hip_runtime.h>
#include <math.h>

// GLIFR (BNNFC) : B=32, T=1000, IN=256, H=512, OUT=128, A=2, DELAY=20
//  ph0: Wsw = bf16(W_lat^T), chunk-permuted so linear global_load_lds writes
//       produce the XOR-swizzled LDS image phase2's MFMA B-frag reads expect.
//  ph1: SYN[t][b][h] = input @ W_iv                      (fp32 tiled GEMM)
//  ph2: 32 INDEPENDENT blocks, one batch element each, all 50 stages inside
//       one plain kernel. F-prev lives in LDS (A operand), W streamed from L2
//       per stage (double-buffered global_load_lds), state in registers.
//       Zero inter-block communication -> no grid.sync, no cooperative launch.
//  ph3: out = F @ out_w + out_b                          (bf16-A tiled GEMM)

constexpr int Bsz   = 32;
constexpr int Tn    = 1000;
constexpr int INn   = 256;
constexpr int Hn    = 512;
constexpr int OUTn  = 128;
constexpr int DELAY = 20;
constexpr int NBLK  = Tn / DELAY;   // 50
constexpr float DTc = 0.05f;
constexpr float Rc  = 0.1f;
constexpr int BH = Bsz * Hn;                  // 16384
constexpr long STG = (long)Bsz * DELAY * Hn;  // 327680 elems per F stage

typedef __attribute__((ext_vector_type(8))) short short8v;  // 8 bf16
typedef __attribute__((ext_vector_type(4))) float f32x4;

__device__ __forceinline__ float sigmoidf_(float x) {
    return 1.0f / (1.0f + expf(-x));
}
__device__ __forceinline__ float bf2f(unsigned short u) {
    return __uint_as_float(((unsigned)u) << 16);
}
__device__ __forceinline__ unsigned short f2bf(float f) {
    unsigned x = __float_as_uint(f);
    return (unsigned short)((x + 0x7fff + ((x >> 16) & 1)) >> 16);  // RNE
}
__device__ __forceinline__ void gl_lds16(const void* g, void* l) {
    __builtin_amdgcn_global_load_lds(
        (const __attribute__((address_space(1))) void*)g,
        (__attribute__((address_space(3))) void*)l, 16, 0, 0);
}

// ---------------------------------------------------------------------------
// fp32 tiled GEMM (phase 1): 64x64 tile, BK=16, 256 thr, 4x4 micro.
// A row m=(t*32+b) maps to input[(b*Tn + t)*K]  (input is [B,T,IN])
// ---------------------------------------------------------------------------
__global__ __launch_bounds__(256) void gemm_ff(
    const float* __restrict__ A, const float* __restrict__ B,
    float* __restrict__ C, int M, int N, int K)
{
    constexpr int BK = 16;
    __shared__ float As[BK][64 + 4];
    __shared__ float Bs[BK][64];

    const int tid = threadIdx.x;
    const int m0 = blockIdx.x * 64;
    const int n0 = blockIdx.y * 64;

    const int la_m  = tid >> 2;
    const int la_kq = (tid & 3) * 4;
    const int m = m0 + la_m;
    const long arow = ((long)(m & 31) * Tn + (m >> 5)) * (long)K;
    const int lb_k = tid >> 4;
    const int lb_n = (tid & 15) * 4;
    const int ty = tid >> 4, tx = tid & 15;

    float acc[4][4] = {};
    for (int k0 = 0; k0 < K; k0 += BK) {
        float4 av = *(const float4*)&A[arow + k0 + la_kq];
        As[la_kq + 0][la_m] = av.x;
        As[la_kq + 1][la_m] = av.y;
        As[la_kq + 2][la_m] = av.z;
        As[la_kq + 3][la_m] = av.w;
        *(float4*)&Bs[lb_k][lb_n] =
            *(const float4*)&B[(long)(k0 + lb_k) * N + n0 + lb_n];
        __syncthreads();
#pragma unroll
        for (int kk = 0; kk < BK; ++kk) {
            float a[4], b[4];
#pragma unroll
            for (int i = 0; i < 4; ++i) a[i] = As[kk][ty * 4 + i];
#pragma unroll
            for (int j = 0; j < 4; ++j) b[j] = Bs[kk][tx * 4 + j];
#pragma unroll
            for (int i = 0; i < 4; ++i)
#pragma unroll
                for (int j = 0; j < 4; ++j)
                    acc[i][j] = fmaf(a[i], b[j], acc[i][j]);
        }
        __syncthreads();
    }
#pragma unroll
    for (int i = 0; i < 4; ++i) {
        long crow = (long)(m0 + ty * 4 + i) * N;
        *(float4*)&C[crow + n0 + tx * 4] =
            make_float4(acc[i][0], acc[i][1], acc[i][2], acc[i][3]);
    }
}

// ---------------------------------------------------------------------------
// W_lat [k][h] fp32 -> Wsw bf16, B^T (n=h major) in k-tiles of 32, with the
// 16B-chunk permutation cg = cl ^ (n&7) baked in, so that a LINEAR
// global_load_lds copy of a 32KB tile yields LDS byte(n,kl) = lin ^ ((n&7)<<4).
// ---------------------------------------------------------------------------
__global__ __launch_bounds__(256) void wlat_cvt(
    const float* __restrict__ W, unsigned short* __restrict__ Wsw)
{
    int e = blockIdx.x * 256 + threadIdx.x;    // e = k*512 + h (coalesced read)
    int kk = e >> 9, h = e & 511;
    int kt = kk >> 5, kl = kk & 31;
    int cl = (h << 2) | (kl >> 3);             // logical 16B chunk within tile
    int cg = cl ^ (h & 7);                     // swizzle-permuted chunk
    Wsw[(long)kt * 16384 + (long)cg * 8 + (kl & 7)] = f2bf(W[e]);
}

// ---------------------------------------------------------------------------
// Phase 2: 32 independent blocks (one per batch b), 256 threads (4 waves).
// Per stage: lateral GEMM C[20 t][512 h] = A_lds(F-prev) x W (streamed),
// fused elementwise recurrence. No inter-block communication at all.
//   A_lds: [32 rows(t, 20 used)][512 k] bf16, XOR-swizzled, written by ew.
//   Wbuf : 2 x [512 n][32 k] bf16 tiles, filled by global_load_lds (linear,
//          source pre-permuted), read as MFMA B-frags.
//   Sy   : [20][516] f32, ff-syn loaded by global_load_lds, epilogue += acc.
// Wave w owns n-strip [w*128, w*128+128) : 8 N-tiles x 2 M-tiles.
// ---------------------------------------------------------------------------
__global__ __launch_bounds__(256, 1) void phase2_bpart(
    const unsigned short* __restrict__ Wsw,
    const float* __restrict__ SYN,
    unsigned short* __restrict__ Fbf,
    const float* __restrict__ tkm, const float* __restrict__ thr,
    const float* __restrict__ aamp, const float* __restrict__ tascr,
    const float* __restrict__ tkasc)
{
    __shared__ unsigned short A_lds[32 * 512];    // 32 KB
    __shared__ unsigned short Wbuf[2][512 * 32];  // 64 KB
    __shared__ float Sy[20][516];                 // 41.3 KB

    const int tid = threadIdx.x;
    const int b = blockIdx.x;
    const int lane = tid & 63, w = tid >> 6;

    // zero A_lds pad rows 20..31 once (M-tile1 rows; stay zero forever)
    {
        uint4 z = make_uint4(0u, 0u, 0u, 0u);
#pragma unroll
        for (int j = 0; j < 3; ++j)
            *(uint4*)((char*)A_lds + 20 * 1024 + (j * 256 + tid) * 16) = z;
    }

    // per-thread ew params: h0 = 2*tid, h1 = 2*tid+1 (computed once)
    const int h0 = tid * 2, h1 = h0 + 1;
    const float dkm0 = sigmoidf_(tkm[h0]), dkm1 = sigmoidf_(tkm[h1]);
    const float th0  = thr[h0],            th1  = thr[h1];
    const float am00 = aamp[h0],           am01 = aamp[h1];
    const float am10 = aamp[Hn + h0],      am11 = aamp[Hn + h1];
    const float rr00 = 1.f - 2.f * sigmoidf_(tascr[h0]);
    const float rr01 = 1.f - 2.f * sigmoidf_(tascr[h1]);
    const float rr10 = 1.f - 2.f * sigmoidf_(tascr[Hn + h0]);
    const float rr11 = 1.f - 2.f * sigmoidf_(tascr[Hn + h1]);
    const float dk00 = sigmoidf_(tkasc[h0]);
    const float dk01 = sigmoidf_(tkasc[h1]);
    const float dk10 = sigmoidf_(tkasc[Hn + h0]);
    const float dk11 = sigmoidf_(tkasc[Hn + h1]);
    const float kR0 = dkm0 * Rc, kR1 = dkm1 * Rc;

    float v0 = 0.f, f0 = 0.f, a00 = 0.f, a10 = 0.f;
    float v1 = 0.f, f1 = 0.f, a01 = 0.f, a11 = 0.f;

    // B-frag byte offsets within a W tile (tile-invariant)
    unsigned blin[8];
#pragma unroll
    for (int nt = 0; nt < 8; ++nt) {
        int n = w * 128 + nt * 16 + (lane & 15);
        blin[nt] = (unsigned)((n * 64 + (lane >> 4) * 16) ^ ((n & 7) << 4));
    }
    // A-frag: row = mt*16 + (lane&15); byte = (row*1024 + kt*64 + q*16) ^ swz
    const int arow0 = (lane & 15), arow1 = 16 + (lane & 15);
    const unsigned alin0 = (unsigned)(arow0 * 1024 + (lane >> 4) * 16);
    const unsigned alin1 = (unsigned)(arow1 * 1024 + (lane >> 4) * 16);
    const unsigned aswz0 = (unsigned)((arow0 & 7) << 4);
    const unsigned aswz1 = (unsigned)((arow1 & 7) << 4);

    __syncthreads();

#pragma unroll 1
    for (int k = 0; k < NBLK; ++k) {
        // issue ff-syn loads into Sy (wave w -> rows w*5..w*5+4), overlap GEMM
#pragma unroll
        for (int i = 0; i < 10; ++i) {
            int c0 = w * 640 + i * 64;           // 16B-chunk base (2560 total)
            int s0 = c0 >> 7, j0 = c0 & 127;     // row, chunk-in-row
            const float* g = SYN + ((long)((k * DELAY + s0) * Bsz + b)) * Hn
                             + (j0 + lane) * 4;
            void* l = (char*)Sy + s0 * 2064 + j0 * 16;
            gl_lds16(g, l);
        }

        if (k > 0) {
            f32x4 acc[2][8] = {};
            // prologue: W k-tile 0 -> Wbuf[0]
#pragma unroll
            for (int j = 0; j < 8; ++j) {
                int c = w * 512 + j * 64 + lane;
                gl_lds16((const char*)Wsw + (long)c * 16,
                         (char*)Wbuf + (w * 512 + j * 64) * 16);
            }
            int cur = 0;
            for (int kt = 0; kt < 16; ++kt) {
                __syncthreads();   // (compiler drains vmcnt) tile kt arrived
                if (kt < 15) {
                    int nb = cur ^ 1;
#pragma unroll
                    for (int j = 0; j < 8; ++j) {
                        int c = w * 512 + j * 64 + lane;
                        gl_lds16((const char*)Wsw + (long)(kt + 1) * 32768
                                     + (long)c * 16,
                                 (char*)Wbuf + nb * 32768
                                     + (w * 512 + j * 64) * 16);
                    }
                }
                short8v afr0 = *(const short8v*)((char*)A_lds
                                   + ((alin0 + kt * 64) ^ aswz0));
                short8v afr1 = *(const short8v*)((char*)A_lds
                                   + ((alin1 + kt * 64) ^ aswz1));
#pragma unroll
                for (int nt = 0; nt < 8; ++nt) {
                    short8v bfr = *(const short8v*)((char*)Wbuf
                                      + cur * 32768 + blin[nt]);
                    acc[0][nt] = __builtin_amdgcn_mfma_f32_16x16x32_bf16(
                        afr0, bfr, acc[0][nt], 0, 0, 0);
                    acc[1][nt] = __builtin_amdgcn_mfma_f32_16x16x32_bf16(
                        afr1, bfr, acc[1][nt], 0, 0, 0);
                }
                cur ^= 1;
            }
            // epilogue: Sy += acc.  C frag: col=lane&15, row=(lane>>4)*4+r
#pragma unroll
            for (int mt = 0; mt < 2; ++mt) {
#pragma unroll
                for (int r = 0; r < 4; ++r) {
                    int row = mt * 16 + (lane >> 4) * 4 + r;
                    if (row < DELAY) {
#pragma unroll
                        for (int nt = 0; nt < 8; ++nt)
                            Sy[row][w * 128 + nt * 16 + (lane & 15)]
                                += acc[mt][nt][r];
                    }
                }
            }
        }
        __syncthreads();   // Sy complete (ff drained + epilogue visible)

        // elementwise recurrence, 20 steps, state in registers
        unsigned short* Fo = Fbf + (long)k * STG + (long)b * DELAY * Hn;
#pragma unroll
        for (int s = 0; s < DELAY; ++s) {
            float2 sv = *(const float2*)((const char*)Sy + s * 2064 + tid * 8);
            a00 = a00 * (rr00 * f0 * DTc + (1.f - dk00)) + am00 * f0 * DTc;
            a10 = a10 * (rr10 * f0 * DTc + (1.f - dk10)) + am10 * f0 * DTc;
            v0 = v0 * (1.f - dkm0 - f0) + kR0 * (sv.x + a00 + a10);
            f0 = sigmoidf_(v0 - th0);
            a01 = a01 * (rr01 * f1 * DTc + (1.f - dk01)) + am01 * f1 * DTc;
            a11 = a11 * (rr11 * f1 * DTc + (1.f - dk11)) + am11 * f1 * DTc;
            v1 = v1 * (1.f - dkm1 - f1) + kR1 * (sv.y + a01 + a11);
            f1 = sigmoidf_(v1 - th1);
            unsigned pk = (unsigned)f2bf(f0) | ((unsigned)f2bf(f1) << 16);
            *(unsigned*)((char*)A_lds
                + ((unsigned)(s * 1024 + tid * 4) ^ ((unsigned)(s & 7) << 4))) = pk;
            *(unsigned*)((char*)Fo + s * 1024 + tid * 4) = pk;
        }
        __syncthreads();   // A_lds ready for next GEMM; Sy free for next loads
    }
}

// ---------------------------------------------------------------------------
// Phase 3: out[b][t][:] = F @ out_w + out_b, A = bf16 stage-blocked F.
// ---------------------------------------------------------------------------
__global__ __launch_bounds__(256) void gemm_out(
    const unsigned short* __restrict__ Fbf, const float* __restrict__ B,
    float* __restrict__ C, const float* __restrict__ bias, int M, int N, int K)
{
    constexpr int BK = 16;
    __shared__ float As[BK][64 + 4];
    __shared__ float Bs[BK][64];

    const int tid = threadIdx.x;
    const int m0 = blockIdx.x * 64;
    const int n0 = blockIdx.y * 64;

    const int la_m  = tid >> 2;
    const int la_kq = (tid & 3) * 4;
    const int m = m0 + la_m;
    const int t = m >> 5, b = m & 31;
    const int ks = t / DELAY, tl = t - ks * DELAY;
    const unsigned short* arow = Fbf + (((long)ks * Bsz + b) * DELAY + tl) * Hn;

    const int lb_k = tid >> 4;
    const int lb_n = (tid & 15) * 4;
    const int ty = tid >> 4, tx = tid & 15;

    float acc[4][4] = {};
    for (int k0 = 0; k0 < K; k0 += BK) {
        const unsigned short* ap = arow + k0 + la_kq;
        As[la_kq + 0][la_m] = bf2f(ap[0]);
        As[la_kq + 1][la_m] = bf2f(ap[1]);
        As[la_kq + 2][la_m] = bf2f(ap[2]);
        As[la_kq + 3][la_m] = bf2f(ap[3]);
        *(float4*)&Bs[lb_k][lb_n] =
            *(const float4*)&B[(long)(k0 + lb_k) * N + n0 + lb_n];
        __syncthreads();
#pragma unroll
        for (int kk = 0; kk < BK; ++kk) {
            float a[4], bvv[4];
#pragma unroll
            for (int i = 0; i < 4; ++i) a[i] = As[kk][ty * 4 + i];
#pragma unroll
            for (int j = 0; j < 4; ++j) bvv[j] = Bs[kk][tx * 4 + j];
#pragma unroll
            for (int i = 0; i < 4; ++i)
#pragma unroll
                for (int j = 0; j < 4; ++j)
                    acc[i][j] = fmaf(a[i], bvv[j], acc[i][j]);
        }
        __syncthreads();
    }
    float4 bv = *(const float4*)&bias[n0 + tx * 4];
#pragma unroll
    for (int i = 0; i < 4; ++i) {
        int mm = m0 + ty * 4 + i;
        long crow = ((long)(mm & 31) * Tn + (mm >> 5)) * (long)N;  // [B,T,OUT]
        float4 v = make_float4(acc[i][0] + bv.x, acc[i][1] + bv.y,
                               acc[i][2] + bv.z, acc[i][3] + bv.w);
        *(float4*)&C[crow + n0 + tx * 4] = v;
    }
}

extern "C" void kernel_launch(void* const* d_in, const int* in_sizes, int n_in,
                              void* d_out, int out_size, void* d_ws, size_t ws_size,
                              hipStream_t stream) {
    const float* input = (const float*)d_in[0];   // [B,T,IN]
    const float* w_iv  = (const float*)d_in[1];   // [IN,H]
    const float* w_lat = (const float*)d_in[2];   // [H,H]
    const float* thr   = (const float*)d_in[3];   // [1,H]
    const float* tkm   = (const float*)d_in[4];   // [1,H]
    const float* aamp  = (const float*)d_in[5];   // [A,1,H]
    const float* tascr = (const float*)d_in[6];   // [A,1,H]
    const float* tkasc = (const float*)d_in[7];   // [A,1,H]
    const float* outw  = (const float*)d_in[8];   // [H,OUT]
    const float* outb  = (const float*)d_in[9];   // [OUT]
    float* out = (float*)d_out;                   // [B,T,OUT]

    const size_t TBH = (size_t)Tn * BH;           // 16,384,000
    float* SYN          = (float*)d_ws;                   // [T][B][H] fp32
    unsigned short* Fbf = (unsigned short*)(SYN + TBH);   // [50][32][20][512] bf16
    unsigned short* Wsw = Fbf + TBH;                      // [16][2048][8] bf16

    const int MTB = Tn * Bsz;                     // 32000

    // Phase 0: convert W_lat -> pre-swizzled bf16 tiles
    wlat_cvt<<<1024, 256, 0, stream>>>(w_lat, Wsw);

    // Phase 1: feedforward GEMM into SYN (time-major [T][B][H], fp32)
    {
        dim3 g(MTB / 64, Hn / 64);
        gemm_ff<<<g, 256, 0, stream>>>(input, w_iv, SYN, MTB, Hn, INn);
    }

    // Phase 2: 32 independent per-batch blocks, all 50 stages internal
    phase2_bpart<<<32, 256, 0, stream>>>(Wsw, SYN, Fbf,
                                         tkm, thr, aamp, tascr, tkasc);

    // Phase 3: output projection, writes [B,T,OUT]
    {
        dim3 g(MTB / 64, OUTn / 64);              // 500 x 2
        gemm_out<<<g, 256, 0, stream>>>(Fbf, outw, out, outb, MTB, OUTn, Hn);
    }
}

// Round 6
// 638.693 us; speedup vs baseline: 1.9516x; 1.3447x over previous
//
#include <hip/hip_runtime.h>
#include <math.h>

// GLIFR (BNNFC) : B=32, T=1000, IN=256, H=512, OUT=128, A=2, DELAY=20
//  ph0: Wsw = bf16(W_lat^T), chunk-permuted so linear global_load_lds writes
//       produce the XOR-swizzled LDS image phase2's MFMA B-frag reads expect.
//  ph1: SYN[t][b][h] = input @ W_iv                      (fp32 tiled GEMM)
//  ph2: 32 independent blocks (one batch element each), 512 thr = 8 waves.
//       Wave-autonomous W streaming: each wave global_load_lds's ONLY its own
//       n-strip slice of each W k-tile -> no cross-wave GEMM hazards -> NO
//       per-tile barriers; counted s_waitcnt vmcnt(N) (ring-3, depth-2).
//       ff-syn in registers; Sy (lateral out) bf16, wave-local.
//       ONE __syncthreads per stage (A_lds handoff).
//  ph3: out = F @ out_w + out_b                          (bf16-A tiled GEMM)

constexpr int Bsz   = 32;
constexpr int Tn    = 1000;
constexpr int INn   = 256;
constexpr int Hn    = 512;
constexpr int OUTn  = 128;
constexpr int DELAY = 20;
constexpr int NBLK  = Tn / DELAY;   // 50
constexpr float DTc = 0.05f;
constexpr float Rc  = 0.1f;
constexpr int BH = Bsz * Hn;                  // 16384
constexpr long STG = (long)Bsz * DELAY * Hn;  // 327680 elems per F stage

typedef __attribute__((ext_vector_type(8))) short short8v;  // 8 bf16
typedef __attribute__((ext_vector_type(4))) float f32x4;

__device__ __forceinline__ float sigmoidf_(float x) {
    return 1.0f / (1.0f + expf(-x));
}
__device__ __forceinline__ float bf2f(unsigned short u) {
    return __uint_as_float(((unsigned)u) << 16);
}
__device__ __forceinline__ unsigned short f2bf(float f) {
    unsigned x = __float_as_uint(f);
    return (unsigned short)((x + 0x7fff + ((x >> 16) & 1)) >> 16);  // RNE
}
__device__ __forceinline__ void gl_lds16(const void* g, void* l) {
    __builtin_amdgcn_global_load_lds(
        (const __attribute__((address_space(1))) void*)g,
        (__attribute__((address_space(3))) void*)l, 16, 0, 0);
}

// ---------------------------------------------------------------------------
// fp32 tiled GEMM (phase 1): 64x64 tile, BK=16, 256 thr, 4x4 micro.
// A row m=(t*32+b) maps to input[(b*Tn + t)*K]  (input is [B,T,IN])
// ---------------------------------------------------------------------------
__global__ __launch_bounds__(256) void gemm_ff(
    const float* __restrict__ A, const float* __restrict__ B,
    float* __restrict__ C, int M, int N, int K)
{
    constexpr int BK = 16;
    __shared__ float As[BK][64 + 4];
    __shared__ float Bs[BK][64];

    const int tid = threadIdx.x;
    const int m0 = blockIdx.x * 64;
    const int n0 = blockIdx.y * 64;

    const int la_m  = tid >> 2;
    const int la_kq = (tid & 3) * 4;
    const int m = m0 + la_m;
    const long arow = ((long)(m & 31) * Tn + (m >> 5)) * (long)K;
    const int lb_k = tid >> 4;
    const int lb_n = (tid & 15) * 4;
    const int ty = tid >> 4, tx = tid & 15;

    float acc[4][4] = {};
    for (int k0 = 0; k0 < K; k0 += BK) {
        float4 av = *(const float4*)&A[arow + k0 + la_kq];
        As[la_kq + 0][la_m] = av.x;
        As[la_kq + 1][la_m] = av.y;
        As[la_kq + 2][la_m] = av.z;
        As[la_kq + 3][la_m] = av.w;
        *(float4*)&Bs[lb_k][lb_n] =
            *(const float4*)&B[(long)(k0 + lb_k) * N + n0 + lb_n];
        __syncthreads();
#pragma unroll
        for (int kk = 0; kk < BK; ++kk) {
            float a[4], b[4];
#pragma unroll
            for (int i = 0; i < 4; ++i) a[i] = As[kk][ty * 4 + i];
#pragma unroll
            for (int j = 0; j < 4; ++j) b[j] = Bs[kk][tx * 4 + j];
#pragma unroll
            for (int i = 0; i < 4; ++i)
#pragma unroll
                for (int j = 0; j < 4; ++j)
                    acc[i][j] = fmaf(a[i], b[j], acc[i][j]);
        }
        __syncthreads();
    }
#pragma unroll
    for (int i = 0; i < 4; ++i) {
        long crow = (long)(m0 + ty * 4 + i) * N;
        *(float4*)&C[crow + n0 + tx * 4] =
            make_float4(acc[i][0], acc[i][1], acc[i][2], acc[i][3]);
    }
}

// ---------------------------------------------------------------------------
// W_lat [k][h] fp32 -> Wsw bf16, B^T (n=h major) in k-tiles of 32, with the
// 16B-chunk permutation cg = cl ^ (n&7) baked in, so that a LINEAR
// global_load_lds copy of a 32KB tile yields LDS byte(n,kl) = lin ^ ((n&7)<<4).
// ---------------------------------------------------------------------------
__global__ __launch_bounds__(256) void wlat_cvt(
    const float* __restrict__ W, unsigned short* __restrict__ Wsw)
{
    int e = blockIdx.x * 256 + threadIdx.x;    // e = k*512 + h (coalesced read)
    int kk = e >> 9, h = e & 511;
    int kt = kk >> 5, kl = kk & 31;
    int cl = (h << 2) | (kl >> 3);             // logical 16B chunk within tile
    int cg = cl ^ (h & 7);                     // swizzle-permuted chunk
    Wsw[(long)kt * 16384 + (long)cg * 8 + (kl & 7)] = f2bf(W[e]);
}

// ---------------------------------------------------------------------------
// Phase 2: 32 independent blocks (one per batch b), 512 threads (8 waves).
// Wave w owns n-strip [w*64, (w+1)*64): streams its own W slice, computes
// 2 M-tiles x 4 N-tiles per k-tile, writes its own Sy strip; ew thread h=tid
// reads its own wave's strip. One barrier per stage (A_lds handoff).
// ---------------------------------------------------------------------------
__global__ __launch_bounds__(512, 1) void phase2_bpart(
    const unsigned short* __restrict__ Wsw,
    const float* __restrict__ SYN,
    unsigned short* __restrict__ Fbf,
    const float* __restrict__ tkm, const float* __restrict__ thr,
    const float* __restrict__ aamp, const float* __restrict__ tascr,
    const float* __restrict__ tkasc)
{
    __shared__ unsigned short A_lds[32 * 512];    // 32 KB, swizzled
    __shared__ unsigned short Wbuf[3][512 * 32];  // 96 KB ring
    __shared__ unsigned short Sy[DELAY][520];     // 20.3 KB, bf16

    const int tid = threadIdx.x;
    const int b = blockIdx.x;
    const int lane = tid & 63, w = tid >> 6;

    // zero A_lds pad rows 20..31 once (never rewritten)
#pragma unroll
    for (int j = 0; j < 2; ++j) {
        int idx = j * 512 + tid;
        if (idx < 768)
            *(uint4*)((char*)A_lds + 20 * 1024 + idx * 16) =
                make_uint4(0u, 0u, 0u, 0u);
    }

    // per-thread ew params: h = tid (computed once)
    const int h = tid;
    const float dkm  = sigmoidf_(tkm[h]);
    const float th   = thr[h];
    const float am0  = aamp[h],       am1 = aamp[Hn + h];
    const float rr0  = 1.f - 2.f * sigmoidf_(tascr[h]);
    const float rr1  = 1.f - 2.f * sigmoidf_(tascr[Hn + h]);
    const float dk0  = sigmoidf_(tkasc[h]);
    const float dk1  = sigmoidf_(tkasc[Hn + h]);
    const float kR   = dkm * Rc;
    float volt = 0.f, fir = 0.f, a0 = 0.f, a1 = 0.f;

    // B-frag byte offsets within a W tile (tile-invariant)
    unsigned blin[4];
#pragma unroll
    for (int nt = 0; nt < 4; ++nt) {
        int n = w * 64 + nt * 16 + (lane & 15);
        blin[nt] = (unsigned)((n * 64 + (lane >> 4) * 16) ^ ((n & 7) << 4));
    }
    // A-frag bases: row = mt*16 + (lane&15)
    const int arow0 = (lane & 15), arow1 = 16 + (lane & 15);
    const unsigned alin0 = (unsigned)(arow0 * 1024 + (lane >> 4) * 16);
    const unsigned alin1 = (unsigned)(arow1 * 1024 + (lane >> 4) * 16);
    const unsigned aswz0 = (unsigned)((arow0 & 7) << 4);
    const unsigned aswz1 = (unsigned)((arow1 & 7) << 4);

    // per-wave W-slice issue: 4 x 1KB chunks per tile
    auto issueW = [&](int kt, int buf) {
#pragma unroll
        for (int j = 0; j < 4; ++j) {
            int c = w * 256 + j * 64 + lane;     // 16B chunk in tile
            gl_lds16((const char*)Wsw + (long)kt * 32768 + (long)c * 16,
                     (char*)Wbuf + buf * 32768 + (w * 256 + j * 64) * 16);
        }
    };

    __syncthreads();

    float ff[DELAY];

#pragma unroll 1
    for (int k = 0; k < NBLK; ++k) {
        const float* synk = SYN + (long)k * DELAY * BH + (long)b * Hn + h;

        if (k == 0) {
#pragma unroll
            for (int s = 0; s < DELAY; ++s)
                ff[s] = synk[(long)s * BH];
        } else {
            f32x4 acc[2][4] = {};
            issueW(0, 0);
            issueW(1, 1);
#pragma unroll
            for (int kt = 0; kt < 16; ++kt) {
                if (kt + 2 < 16) issueW(kt + 2, (kt + 2) % 3);
                if (kt == 12) {
                    // issue ff loads here: HBM latency hides under tiles 12-15
#pragma unroll
                    for (int s = 0; s < DELAY; ++s)
                        ff[s] = synk[(long)s * BH];
                }
                // counted wait: W(kt) arrived (per-wave FIFO arithmetic)
                if (kt < 12)       asm volatile("s_waitcnt vmcnt(8)" ::: "memory");
                else if (kt < 14)  asm volatile("s_waitcnt vmcnt(28)" ::: "memory");
                else if (kt == 14) asm volatile("s_waitcnt vmcnt(24)" ::: "memory");
                else               asm volatile("s_waitcnt vmcnt(20)" ::: "memory");
                __builtin_amdgcn_sched_barrier(0);

                const int buf = kt % 3;
                short8v afr0 = *(const short8v*)((char*)A_lds
                                   + ((alin0 + kt * 64) ^ aswz0));
                short8v afr1 = *(const short8v*)((char*)A_lds
                                   + ((alin1 + kt * 64) ^ aswz1));
#pragma unroll
                for (int nt = 0; nt < 4; ++nt) {
                    short8v bfr = *(const short8v*)((char*)Wbuf
                                      + buf * 32768 + blin[nt]);
                    acc[0][nt] = __builtin_amdgcn_mfma_f32_16x16x32_bf16(
                        afr0, bfr, acc[0][nt], 0, 0, 0);
                    acc[1][nt] = __builtin_amdgcn_mfma_f32_16x16x32_bf16(
                        afr1, bfr, acc[1][nt], 0, 0, 0);
                }
            }
            // epilogue: acc -> Sy (own strip, bf16). C frag: col=lane&15,
            // row=(lane>>4)*4+r
#pragma unroll
            for (int mt = 0; mt < 2; ++mt)
#pragma unroll
                for (int r = 0; r < 4; ++r) {
                    int row = mt * 16 + (lane >> 4) * 4 + r;
                    if (row < DELAY) {
#pragma unroll
                        for (int nt = 0; nt < 4; ++nt)
                            Sy[row][w * 64 + nt * 16 + (lane & 15)]
                                = f2bf(acc[mt][nt][r]);
                    }
                }
        }

        // ---- elementwise recurrence (20 steps); Sy strip is wave-local so
        // same-wave lgkmcnt ordering suffices (no barrier before this).
        unsigned short* Fo = Fbf + (long)k * STG + (long)b * DELAY * Hn + h;
#pragma unroll
        for (int s = 0; s < DELAY; ++s) {
            float sv = ff[s];
            if (k > 0) sv += bf2f(Sy[s][tid]);
            a0 = a0 * (rr0 * fir * DTc + (1.f - dk0)) + am0 * fir * DTc;
            a1 = a1 * (rr1 * fir * DTc + (1.f - dk1)) + am1 * fir * DTc;
            volt = volt * (1.f - dkm - fir) + kR * (sv + a0 + a1);
            fir = sigmoidf_(volt - th);
            unsigned short fb = f2bf(fir);
            *(unsigned short*)((char*)A_lds
                + ((unsigned)(s * 1024 + h * 2) ^ ((unsigned)(s & 7) << 4))) = fb;
            Fo[(long)s * Hn] = fb;
        }
        __syncthreads();   // A_lds ready for all waves' next-stage MFMA
    }
}

// ---------------------------------------------------------------------------
// Phase 3: out[b][t][:] = F @ out_w + out_b, A = bf16 stage-blocked F.
// ---------------------------------------------------------------------------
__global__ __launch_bounds__(256) void gemm_out(
    const unsigned short* __restrict__ Fbf, const float* __restrict__ B,
    float* __restrict__ C, const float* __restrict__ bias, int M, int N, int K)
{
    constexpr int BK = 16;
    __shared__ float As[BK][64 + 4];
    __shared__ float Bs[BK][64];

    const int tid = threadIdx.x;
    const int m0 = blockIdx.x * 64;
    const int n0 = blockIdx.y * 64;

    const int la_m  = tid >> 2;
    const int la_kq = (tid & 3) * 4;
    const int m = m0 + la_m;
    const int t = m >> 5, b = m & 31;
    const int ks = t / DELAY, tl = t - ks * DELAY;
    const unsigned short* arow = Fbf + (((long)ks * Bsz + b) * DELAY + tl) * Hn;

    const int lb_k = tid >> 4;
    const int lb_n = (tid & 15) * 4;
    const int ty = tid >> 4, tx = tid & 15;

    float acc[4][4] = {};
    for (int k0 = 0; k0 < K; k0 += BK) {
        const unsigned short* ap = arow + k0 + la_kq;
        As[la_kq + 0][la_m] = bf2f(ap[0]);
        As[la_kq + 1][la_m] = bf2f(ap[1]);
        As[la_kq + 2][la_m] = bf2f(ap[2]);
        As[la_kq + 3][la_m] = bf2f(ap[3]);
        *(float4*)&Bs[lb_k][lb_n] =
            *(const float4*)&B[(long)(k0 + lb_k) * N + n0 + lb_n];
        __syncthreads();
#pragma unroll
        for (int kk = 0; kk < BK; ++kk) {
            float a[4], bvv[4];
#pragma unroll
            for (int i = 0; i < 4; ++i) a[i] = As[kk][ty * 4 + i];
#pragma unroll
            for (int j = 0; j < 4; ++j) bvv[j] = Bs[kk][tx * 4 + j];
#pragma unroll
            for (int i = 0; i < 4; ++i)
#pragma unroll
                for (int j = 0; j < 4; ++j)
                    acc[i][j] = fmaf(a[i], bvv[j], acc[i][j]);
        }
        __syncthreads();
    }
    float4 bv = *(const float4*)&bias[n0 + tx * 4];
#pragma unroll
    for (int i = 0; i < 4; ++i) {
        int mm = m0 + ty * 4 + i;
        long crow = ((long)(mm & 31) * Tn + (mm >> 5)) * (long)N;  // [B,T,OUT]
        float4 v = make_float4(acc[i][0] + bv.x, acc[i][1] + bv.y,
                               acc[i][2] + bv.z, acc[i][3] + bv.w);
        *(float4*)&C[crow + n0 + tx * 4] = v;
    }
}

extern "C" void kernel_launch(void* const* d_in, const int* in_sizes, int n_in,
                              void* d_out, int out_size, void* d_ws, size_t ws_size,
                              hipStream_t stream) {
    const float* input = (const float*)d_in[0];   // [B,T,IN]
    const float* w_iv  = (const float*)d_in[1];   // [IN,H]
    const float* w_lat = (const float*)d_in[2];   // [H,H]
    const float* thr   = (const float*)d_in[3];   // [1,H]
    const float* tkm   = (const float*)d_in[4];   // [1,H]
    const float* aamp  = (const float*)d_in[5];   // [A,1,H]
    const float* tascr = (const float*)d_in[6];   // [A,1,H]
    const float* tkasc = (const float*)d_in[7];   // [A,1,H]
    const float* outw  = (const float*)d_in[8];   // [H,OUT]
    const float* outb  = (const float*)d_in[9];   // [OUT]
    float* out = (float*)d_out;                   // [B,T,OUT]

    const size_t TBH = (size_t)Tn * BH;           // 16,384,000
    float* SYN          = (float*)d_ws;                   // [T][B][H] fp32
    unsigned short* Fbf = (unsigned short*)(SYN + TBH);   // [50][32][20][512] bf16
    unsigned short* Wsw = Fbf + TBH;                      // [16][16384] bf16

    const int MTB = Tn * Bsz;                     // 32000

    // Phase 0: convert W_lat -> pre-swizzled bf16 tiles
    wlat_cvt<<<1024, 256, 0, stream>>>(w_lat, Wsw);

    // Phase 1: feedforward GEMM into SYN (time-major [T][B][H], fp32)
    {
        dim3 g(MTB / 64, Hn / 64);
        gemm_ff<<<g, 256, 0, stream>>>(input, w_iv, SYN, MTB, Hn, INn);
    }

    // Phase 2: 32 independent per-batch blocks, all 50 stages internal
    phase2_bpart<<<32, 512, 0, stream>>>(Wsw, SYN, Fbf,
                                         tkm, thr, aamp, tascr, tkasc);

    // Phase 3: output projection, writes [B,T,OUT]
    {
        dim3 g(MTB / 64, OUTn / 64);              // 500 x 2
        gemm_out<<<g, 256, 0, stream>>>(Fbf, outw, out, outb, MTB, OUTn, Hn);
    }
}

// Round 7
// 559.408 us; speedup vs baseline: 2.2282x; 1.1417x over previous
//
#include <hip/hip_runtime.h>
#include <math.h>

// GLIFR (BNNFC) : B=32, T=1000, IN=256, H=512, OUT=128, A=2, DELAY=20
//  ph0: Wq[h][k] = fp8_e4m3(W_lat[k][h])                 (transpose+quantize)
//  ph1: SYN[t][b][h] = input @ W_iv                      (fp32 tiled GEMM)
//  ph2: 32 independent blocks (one batch each), 512 thr = 8 waves.
//       W FP8 FRAGMENTS RESIDENT IN REGISTERS (128 VGPR/wave, loaded once);
//       A (firing) fp8 in double-buffered LDS; fp8 MFMA; zero VMEM in the
//       K-loop; one barrier per stage.
//  ph3: out = F @ out_w + out_b                          (bf16-A tiled GEMM)

constexpr int Bsz   = 32;
constexpr int Tn    = 1000;
constexpr int INn   = 256;
constexpr int Hn    = 512;
constexpr int OUTn  = 128;
constexpr int DELAY = 20;
constexpr int NBLK  = Tn / DELAY;   // 50
constexpr float DTc = 0.05f;
constexpr float Rc  = 0.1f;
constexpr int BH = Bsz * Hn;                  // 16384
constexpr long STG = (long)Bsz * DELAY * Hn;  // 327680 elems per F stage

typedef __attribute__((ext_vector_type(4))) float f32x4;

__device__ __forceinline__ float sigmoidf_(float x) {
    return 1.0f / (1.0f + expf(-x));
}
__device__ __forceinline__ float bf2f(unsigned short u) {
    return __uint_as_float(((unsigned)u) << 16);
}
__device__ __forceinline__ unsigned short f2bf(float f) {
    unsigned x = __float_as_uint(f);
    return (unsigned short)((x + 0x7fff + ((x >> 16) & 1)) >> 16);  // RNE
}
// OCP e4m3fn encode, RNE, |x| < 448 assumed (here |x| <= ~1)
__device__ __forceinline__ unsigned char f2e4m3(float x) {
    unsigned b = __float_as_uint(x);
    unsigned s = (b >> 31) << 7;
    b &= 0x7fffffffu;
    unsigned code;
    if (__uint_as_float(b) < 0.015625f) {            // |x| < 2^-6: subnormal
        code = (unsigned)__float2int_rn(__uint_as_float(b) * 512.0f);
    } else {
        unsigned r = b + 0x7ffffu + ((b >> 20) & 1); // RNE at 3 mantissa bits
        int e = (int)(r >> 23) - 127;
        code = (unsigned)(((e + 7) << 3) | ((r >> 20) & 7));
    }
    return (unsigned char)(s | code);
}

// ---------------------------------------------------------------------------
// fp32 tiled GEMM (phase 1): 64x64 tile, BK=16, 256 thr, 4x4 micro.
// A row m=(t*32+b) maps to input[(b*Tn + t)*K]  (input is [B,T,IN])
// ---------------------------------------------------------------------------
__global__ __launch_bounds__(256) void gemm_ff(
    const float* __restrict__ A, const float* __restrict__ B,
    float* __restrict__ C, int M, int N, int K)
{
    constexpr int BK = 16;
    __shared__ float As[BK][64 + 4];
    __shared__ float Bs[BK][64];

    const int tid = threadIdx.x;
    const int m0 = blockIdx.x * 64;
    const int n0 = blockIdx.y * 64;

    const int la_m  = tid >> 2;
    const int la_kq = (tid & 3) * 4;
    const int m = m0 + la_m;
    const long arow = ((long)(m & 31) * Tn + (m >> 5)) * (long)K;
    const int lb_k = tid >> 4;
    const int lb_n = (tid & 15) * 4;
    const int ty = tid >> 4, tx = tid & 15;

    float acc[4][4] = {};
    for (int k0 = 0; k0 < K; k0 += BK) {
        float4 av = *(const float4*)&A[arow + k0 + la_kq];
        As[la_kq + 0][la_m] = av.x;
        As[la_kq + 1][la_m] = av.y;
        As[la_kq + 2][la_m] = av.z;
        As[la_kq + 3][la_m] = av.w;
        *(float4*)&Bs[lb_k][lb_n] =
            *(const float4*)&B[(long)(k0 + lb_k) * N + n0 + lb_n];
        __syncthreads();
#pragma unroll
        for (int kk = 0; kk < BK; ++kk) {
            float a[4], b[4];
#pragma unroll
            for (int i = 0; i < 4; ++i) a[i] = As[kk][ty * 4 + i];
#pragma unroll
            for (int j = 0; j < 4; ++j) b[j] = Bs[kk][tx * 4 + j];
#pragma unroll
            for (int i = 0; i < 4; ++i)
#pragma unroll
                for (int j = 0; j < 4; ++j)
                    acc[i][j] = fmaf(a[i], b[j], acc[i][j]);
        }
        __syncthreads();
    }
#pragma unroll
    for (int i = 0; i < 4; ++i) {
        long crow = (long)(m0 + ty * 4 + i) * N;
        *(float4*)&C[crow + n0 + tx * 4] =
            make_float4(acc[i][0], acc[i][1], acc[i][2], acc[i][3]);
    }
}

// ---------------------------------------------------------------------------
// W_lat [k][h] fp32 -> Wq [h][k] fp8 e4m3 (transposed), 32x32 LDS tiles
// ---------------------------------------------------------------------------
__global__ __launch_bounds__(256) void wlat_cvt(
    const float* __restrict__ W, unsigned char* __restrict__ Wq)
{
    __shared__ float tile[32][33];
    const int tid = threadIdx.x;
    const int bx = blockIdx.x & 15, by = blockIdx.x >> 4;
    const int x = tid & 31, y = tid >> 5;   // 32 x 8
#pragma unroll
    for (int j = 0; j < 4; ++j)
        tile[y + j * 8][x] = W[(long)(by * 32 + y + j * 8) * Hn + bx * 32 + x];
    __syncthreads();
#pragma unroll
    for (int j = 0; j < 4; ++j)
        Wq[(long)(bx * 32 + y + j * 8) * Hn + by * 32 + x] =
            f2e4m3(tile[x][y + j * 8]);
}

// ---------------------------------------------------------------------------
// Phase 2: 32 independent blocks (one per batch b), 512 threads (8 waves).
// Wave w owns n-strip [w*64, (w+1)*64). Its W slice lives in 128 VGPRs as
// fp8 MFMA B-fragments, loaded once. Per stage: GEMM (LDS A-frags + MFMA,
// no memory waits), epilogue -> Sy (wave-local), ew recurrence (state in
// regs), firing -> fp8 into the OTHER A_lds buffer + bf16 to global.
// One __syncthreads per stage.
// ---------------------------------------------------------------------------
__global__ __launch_bounds__(512, 1) void phase2_bpart(
    const unsigned char* __restrict__ Wq,    // [512 n][512 k] fp8
    const float* __restrict__ SYN,
    unsigned short* __restrict__ Fbf,
    const float* __restrict__ tkm, const float* __restrict__ thr,
    const float* __restrict__ aamp, const float* __restrict__ tascr,
    const float* __restrict__ tkasc)
{
    __shared__ unsigned char A_lds[2][32 * 512];  // 2 x 16 KB fp8, swizzled
    __shared__ unsigned short Sy[DELAY][520];     // 20.3 KB bf16

    const int tid = threadIdx.x;
    const int b = blockIdx.x;
    const int lane = tid & 63, w = tid >> 6;

    // zero both A buffers (covers pad rows 20..31 forever)
#pragma unroll
    for (int j = 0; j < 4; ++j)
        *(uint4*)(&A_lds[0][0] + (j * 512 + tid) * 16) = make_uint4(0u,0u,0u,0u);

    // ---- W fragments -> registers (once). B-frag: col n = lane&15,
    // k-chunk = (lane>>4)*8 contiguous fp8 bytes. Self-consistent with A-frag.
    long long wreg[16][4];
#pragma unroll
    for (int kt = 0; kt < 16; ++kt)
#pragma unroll
        for (int nt = 0; nt < 4; ++nt) {
            int n = w * 64 + nt * 16 + (lane & 15);
            int kk = kt * 32 + (lane >> 4) * 8;
            wreg[kt][nt] = *(const long long*)&Wq[(long)n * Hn + kk];
        }

    // ---- per-thread ew params: h = tid (computed once)
    const int h = tid;
    const float dkm  = sigmoidf_(tkm[h]);
    const float th   = thr[h];
    const float am0  = aamp[h],       am1 = aamp[Hn + h];
    const float rr0  = 1.f - 2.f * sigmoidf_(tascr[h]);
    const float rr1  = 1.f - 2.f * sigmoidf_(tascr[Hn + h]);
    const float dk0  = sigmoidf_(tkasc[h]);
    const float dk1  = sigmoidf_(tkasc[Hn + h]);
    const float kR   = dkm * Rc;
    float volt = 0.f, fir = 0.f, a0 = 0.f, a1 = 0.f;

    // A-frag byte offsets (row = mt*16 + (lane&15); 8B chunk (lane>>4)*8;
    // XOR swizzle bits 3..5 with row&7, applied after adding kt*32)
    const int ar0 = lane & 15, ar1 = 16 + (lane & 15);
    const unsigned a0base = (unsigned)(ar0 * 512 + (lane >> 4) * 8);
    const unsigned a1base = (unsigned)(ar1 * 512 + (lane >> 4) * 8);
    const unsigned swz0 = (unsigned)((ar0 & 7) << 3);
    const unsigned swz1 = (unsigned)((ar1 & 7) << 3);

    __syncthreads();

#pragma unroll 1
    for (int k = 0; k < NBLK; ++k) {
        // issue ff-syn loads first: latency hides under the GEMM
        const float* synk = SYN + (long)k * DELAY * BH + (long)b * Hn + h;
        float ff[DELAY];
#pragma unroll
        for (int s = 0; s < DELAY; ++s)
            ff[s] = synk[(long)s * BH];

        if (k > 0) {
            const unsigned char* Ab = &A_lds[k & 1][0];
            f32x4 acc[2][4] = {};
#pragma unroll
            for (int kt = 0; kt < 16; ++kt) {
                long long afr0 = *(const long long*)(Ab + ((a0base + kt * 32) ^ swz0));
                long long afr1 = *(const long long*)(Ab + ((a1base + kt * 32) ^ swz1));
#pragma unroll
                for (int nt = 0; nt < 4; ++nt) {
                    acc[0][nt] = __builtin_amdgcn_mfma_f32_16x16x32_fp8_fp8(
                        afr0, wreg[kt][nt], acc[0][nt], 0, 0, 0);
                    acc[1][nt] = __builtin_amdgcn_mfma_f32_16x16x32_fp8_fp8(
                        afr1, wreg[kt][nt], acc[1][nt], 0, 0, 0);
                }
            }
            // epilogue -> Sy (own strip, bf16). C frag: col=lane&15,
            // row=(lane>>4)*4+r
#pragma unroll
            for (int mt = 0; mt < 2; ++mt)
#pragma unroll
                for (int r = 0; r < 4; ++r) {
                    int row = mt * 16 + (lane >> 4) * 4 + r;
                    if (row < DELAY) {
#pragma unroll
                        for (int nt = 0; nt < 4; ++nt)
                            Sy[row][w * 64 + nt * 16 + (lane & 15)]
                                = f2bf(acc[mt][nt][r]);
                    }
                }
        }

        // ---- elementwise recurrence (20 steps); Sy strip is wave-local.
        // firing -> fp8 into A_lds[(k+1)&1] (read by ALL waves next stage,
        // protected by the stage-end barrier) + bf16 to global for ph3.
        unsigned char* An = &A_lds[(k + 1) & 1][0];
        unsigned short* Fo = Fbf + (long)k * STG + (long)b * DELAY * Hn + h;
#pragma unroll
        for (int s = 0; s < DELAY; ++s) {
            float sv = ff[s];
            if (k > 0) sv += bf2f(Sy[s][tid]);
            a0 = a0 * (rr0 * fir * DTc + (1.f - dk0)) + am0 * fir * DTc;
            a1 = a1 * (rr1 * fir * DTc + (1.f - dk1)) + am1 * fir * DTc;
            volt = volt * (1.f - dkm - fir) + kR * (sv + a0 + a1);
            fir = sigmoidf_(volt - th);
            An[(unsigned)(s * 512 + h) ^ ((unsigned)(s & 7) << 3)] = f2e4m3(fir);
            Fo[(long)s * Hn] = f2bf(fir);
        }
        __syncthreads();   // A_lds[(k+1)&1] complete for all waves' next GEMM
    }
}

// ---------------------------------------------------------------------------
// Phase 3: out[b][t][:] = F @ out_w + out_b, A = bf16 stage-blocked F.
// ---------------------------------------------------------------------------
__global__ __launch_bounds__(256) void gemm_out(
    const unsigned short* __restrict__ Fbf, const float* __restrict__ B,
    float* __restrict__ C, const float* __restrict__ bias, int M, int N, int K)
{
    constexpr int BK = 16;
    __shared__ float As[BK][64 + 4];
    __shared__ float Bs[BK][64];

    const int tid = threadIdx.x;
    const int m0 = blockIdx.x * 64;
    const int n0 = blockIdx.y * 64;

    const int la_m  = tid >> 2;
    const int la_kq = (tid & 3) * 4;
    const int m = m0 + la_m;
    const int t = m >> 5, b = m & 31;
    const int ks = t / DELAY, tl = t - ks * DELAY;
    const unsigned short* arow = Fbf + (((long)ks * Bsz + b) * DELAY + tl) * Hn;

    const int lb_k = tid >> 4;
    const int lb_n = (tid & 15) * 4;
    const int ty = tid >> 4, tx = tid & 15;

    float acc[4][4] = {};
    for (int k0 = 0; k0 < K; k0 += BK) {
        const unsigned short* ap = arow + k0 + la_kq;
        As[la_kq + 0][la_m] = bf2f(ap[0]);
        As[la_kq + 1][la_m] = bf2f(ap[1]);
        As[la_kq + 2][la_m] = bf2f(ap[2]);
        As[la_kq + 3][la_m] = bf2f(ap[3]);
        *(float4*)&Bs[lb_k][lb_n] =
            *(const float4*)&B[(long)(k0 + lb_k) * N + n0 + lb_n];
        __syncthreads();
#pragma unroll
        for (int kk = 0; kk < BK; ++kk) {
            float a[4], bvv[4];
#pragma unroll
            for (int i = 0; i < 4; ++i) a[i] = As[kk][ty * 4 + i];
#pragma unroll
            for (int j = 0; j < 4; ++j) bvv[j] = Bs[kk][tx * 4 + j];
#pragma unroll
            for (int i = 0; i < 4; ++i)
#pragma unroll
                for (int j = 0; j < 4; ++j)
                    acc[i][j] = fmaf(a[i], bvv[j], acc[i][j]);
        }
        __syncthreads();
    }
    float4 bv = *(const float4*)&bias[n0 + tx * 4];
#pragma unroll
    for (int i = 0; i < 4; ++i) {
        int mm = m0 + ty * 4 + i;
        long crow = ((long)(mm & 31) * Tn + (mm >> 5)) * (long)N;  // [B,T,OUT]
        float4 v = make_float4(acc[i][0] + bv.x, acc[i][1] + bv.y,
                               acc[i][2] + bv.z, acc[i][3] + bv.w);
        *(float4*)&C[crow + n0 + tx * 4] = v;
    }
}

extern "C" void kernel_launch(void* const* d_in, const int* in_sizes, int n_in,
                              void* d_out, int out_size, void* d_ws, size_t ws_size,
                              hipStream_t stream) {
    const float* input = (const float*)d_in[0];   // [B,T,IN]
    const float* w_iv  = (const float*)d_in[1];   // [IN,H]
    const float* w_lat = (const float*)d_in[2];   // [H,H]
    const float* thr   = (const float*)d_in[3];   // [1,H]
    const float* tkm   = (const float*)d_in[4];   // [1,H]
    const float* aamp  = (const float*)d_in[5];   // [A,1,H]
    const float* tascr = (const float*)d_in[6];   // [A,1,H]
    const float* tkasc = (const float*)d_in[7];   // [A,1,H]
    const float* outw  = (const float*)d_in[8];   // [H,OUT]
    const float* outb  = (const float*)d_in[9];   // [OUT]
    float* out = (float*)d_out;                   // [B,T,OUT]

    const size_t TBH = (size_t)Tn * BH;           // 16,384,000
    float* SYN          = (float*)d_ws;                   // [T][B][H] fp32
    unsigned short* Fbf = (unsigned short*)(SYN + TBH);   // [50][32][20][512] bf16
    unsigned char* Wq   = (unsigned char*)(Fbf + TBH);    // [512][512] fp8

    const int MTB = Tn * Bsz;                     // 32000

    // Phase 0: convert+transpose W_lat -> fp8 e4m3 [h][k]
    wlat_cvt<<<256, 256, 0, stream>>>(w_lat, Wq);

    // Phase 1: feedforward GEMM into SYN (time-major [T][B][H], fp32)
    {
        dim3 g(MTB / 64, Hn / 64);
        gemm_ff<<<g, 256, 0, stream>>>(input, w_iv, SYN, MTB, Hn, INn);
    }

    // Phase 2: 32 independent per-batch blocks, all 50 stages internal
    phase2_bpart<<<32, 512, 0, stream>>>(Wq, SYN, Fbf,
                                         tkm, thr, aamp, tascr, tkasc);

    // Phase 3: output projection, writes [B,T,OUT]
    {
        dim3 g(MTB / 64, OUTn / 64);              // 500 x 2
        gemm_out<<<g, 256, 0, stream>>>(Fbf, outw, out, outb, MTB, OUTn, Hn);
    }
}

// Round 9
// 390.591 us; speedup vs baseline: 3.1912x; 1.4322x over previous
//
#include <hip/hip_runtime.h>
#include <math.h>

// GLIFR (BNNFC) : B=32, T=1000, IN=256, H=512, OUT=128, A=2, DELAY=20
//  cvts: input->Abf (blocked bf16), W_iv/out_w -> blocked bf16, W_lat -> fp8
//  ph1: SYN = input @ W_iv          (bf16 MFMA GEMM, blocked operands)
//  ph2: 32 independent blocks, W fp8 resident in regs (256-VGPR cap via
//       amdgpu_waves_per_eu(2,2) -- R7 spilled at 128), fast sigmoid,
//       F written in ph3's blocked layout
//  ph3: out = F @ out_w + out_b     (bf16 MFMA GEMM)
//  R9 fix: F3 m-tile stride 8192 -> 65536 (ph3 A-tile = KT·8192 elems).

constexpr int Bsz   = 32;
constexpr int Tn    = 1000;
constexpr int INn   = 256;
constexpr int Hn    = 512;
constexpr int OUTn  = 128;
constexpr int DELAY = 20;
constexpr int NBLK  = Tn / DELAY;   // 50
constexpr float DTc = 0.05f;
constexpr float Rc  = 0.1f;
constexpr int BH = Bsz * Hn;                  // 16384

typedef __attribute__((ext_vector_type(8))) short short8v;  // 8 bf16
typedef __attribute__((ext_vector_type(4))) float f32x4;

__device__ __forceinline__ float sigmoidf_(float x) {
    return 1.0f / (1.0f + expf(-x));
}
__device__ __forceinline__ float sigfast_(float x) {
    // 1/(1+2^(-x*log2e)) : v_exp_f32 + v_rcp_f32
    return __builtin_amdgcn_rcpf(1.0f + __builtin_amdgcn_exp2f(x * -1.44269504f));
}
__device__ __forceinline__ float bf2f(unsigned short u) {
    return __uint_as_float(((unsigned)u) << 16);
}
__device__ __forceinline__ unsigned short f2bf(float f) {
    unsigned x = __float_as_uint(f);
    return (unsigned short)((x + 0x7fff + ((x >> 16) & 1)) >> 16);  // RNE
}
// OCP e4m3fn encode, RNE, |x| small
__device__ __forceinline__ unsigned char f2e4m3(float x) {
    unsigned b = __float_as_uint(x);
    unsigned s = (b >> 31) << 7;
    b &= 0x7fffffffu;
    unsigned code;
    if (__uint_as_float(b) < 0.015625f) {            // |x| < 2^-6: subnormal
        code = (unsigned)__float2int_rn(__uint_as_float(b) * 512.0f);
    } else {
        unsigned r = b + 0x7ffffu + ((b >> 20) & 1); // RNE at 3 mantissa bits
        int e = (int)(r >> 23) - 127;
        code = (unsigned)(((e + 7) << 3) | ((r >> 20) & 7));
    }
    return (unsigned char)(s | code);
}
__device__ __forceinline__ void gl_lds16(const void* g, void* l) {
    __builtin_amdgcn_global_load_lds(
        (const __attribute__((address_space(1))) void*)g,
        (__attribute__((address_space(3))) void*)l, 16, 0, 0);
}

// ---------------------------------------------------------------------------
// input [B,T,IN] fp32 -> Abf blocked bf16 [mtile 250][kt 4][kq 8][row 128][e 8]
// block = (mtile, kt); LDS transpose so both sides are coalesced/contiguous.
// ---------------------------------------------------------------------------
__global__ __launch_bounds__(256) void cvt_in(
    const float* __restrict__ in, unsigned short* __restrict__ Abf)
{
    __shared__ float t[128][65];
    const int tid = threadIdx.x;
    const int mtile = blockIdx.x >> 2, kt = blockIdx.x & 3;
    const int rr = tid >> 4, cc = (tid & 15) * 4;
#pragma unroll
    for (int j = 0; j < 8; ++j) {
        int row = j * 16 + rr;
        int m = mtile * 128 + row;
        float4 v = *(const float4*)
            &in[((long)(m & 31) * Tn + (m >> 5)) * INn + kt * 64 + cc];
        t[row][cc] = v.x; t[row][cc + 1] = v.y;
        t[row][cc + 2] = v.z; t[row][cc + 3] = v.w;
    }
    __syncthreads();
    unsigned short* dst = Abf + (long)(mtile * 4 + kt) * 8192;
#pragma unroll
    for (int j = 0; j < 4; ++j) {
        int q = tid + 256 * j;
        int kq = q >> 7, row = q & 127;
        short8v o;
#pragma unroll
        for (int i = 0; i < 8; ++i) o[i] = (short)f2bf(t[row][kq * 8 + i]);
        *(short8v*)&dst[(long)q * 8] = o;
    }
}

// ---------------------------------------------------------------------------
// Weight [K][NG] fp32 -> blocked bf16 B^T tiles [ntile][KT_][kq 8][n 64][e 8]
// one thread per 16B output chunk; gather reads (small matrices).
// ---------------------------------------------------------------------------
template<int KT_, int NG>
__global__ __launch_bounds__(256) void cvt_b(
    const float* __restrict__ Wg, unsigned short* __restrict__ Bb)
{
    int c = blockIdx.x * 256 + threadIdx.x;     // ((ntile*KT_+kt)*8+kq)*64+n
    int n = c & 63;
    int c2 = c >> 6;
    int kq = c2 & 7;
    int c3 = c2 >> 3;
    int kt = c3 % KT_, ntile = c3 / KT_;
    short8v o;
#pragma unroll
    for (int i = 0; i < 8; ++i)
        o[i] = (short)f2bf(Wg[(long)(kt * 64 + kq * 8 + i) * NG + ntile * 64 + n]);
    *(short8v*)&Bb[(long)c * 8] = o;
}

// ---------------------------------------------------------------------------
// W_lat [k][h] fp32 -> Wq [h][k] fp8 e4m3 (transposed), 32x32 LDS tiles
// ---------------------------------------------------------------------------
__global__ __launch_bounds__(256) void wlat_cvt(
    const float* __restrict__ W, unsigned char* __restrict__ Wq)
{
    __shared__ float tile[32][33];
    const int tid = threadIdx.x;
    const int bx = blockIdx.x & 15, by = blockIdx.x >> 4;
    const int x = tid & 31, y = tid >> 5;   // 32 x 8
#pragma unroll
    for (int j = 0; j < 4; ++j)
        tile[y + j * 8][x] = W[(long)(by * 32 + y + j * 8) * Hn + bx * 32 + x];
    __syncthreads();
#pragma unroll
    for (int j = 0; j < 4; ++j)
        Wq[(long)(bx * 32 + y + j * 8) * Hn + by * 32 + x] =
            f2e4m3(tile[x][y + j * 8]);
}

// ---------------------------------------------------------------------------
// bf16 MFMA GEMM: 128x64 tile, BK=64, 256 thr (4 waves, wave owns 32 rows).
// A blocked [mtile][KT][kq 8][row 128][8], B blocked [ntile][KT][kq 8][n 64][8]
// (16-lane frag groups read at 16B stride -> conflict-free ds_read_b128).
// Single barrier per K-iter; global_load_lds double-buffer.
// OUT_BT: C row m -> out[(m&31)*Tn + (m>>5)] (i.e. [B,T,N]); else C + m*N.
// ---------------------------------------------------------------------------
template<int KT, bool OUT_BT, bool BIAS>
__global__ __launch_bounds__(256) void gemm_mfma(
    const unsigned short* __restrict__ A, const unsigned short* __restrict__ Bm,
    float* __restrict__ C, const float* __restrict__ bias, int N)
{
    __shared__ unsigned short Asl[2][8192];   // 2 x 16 KB
    __shared__ unsigned short Bsl[2][4096];   // 2 x 8 KB

    const int tid = threadIdx.x, lane = tid & 63, w = tid >> 6;
    const int ntile = blockIdx.x, mtile = blockIdx.y;
    const unsigned short* Abase = A + (long)mtile * KT * 8192;
    const unsigned short* Bbase = Bm + (long)ntile * KT * 4096;

    auto stageA = [&](int kt, int buf) {
#pragma unroll
        for (int j = 0; j < 4; ++j) {
            int c = tid + 256 * j;
            gl_lds16(Abase + (long)kt * 8192 + (long)c * 8, &Asl[buf][c * 8]);
        }
    };
    auto stageB = [&](int kt, int buf) {
#pragma unroll
        for (int j = 0; j < 2; ++j) {
            int c = tid + 256 * j;
            gl_lds16(Bbase + (long)kt * 4096 + (long)c * 8, &Bsl[buf][c * 8]);
        }
    };

    f32x4 acc[2][4] = {};
    stageA(0, 0); stageB(0, 0);
    int cur = 0;
#pragma unroll
    for (int kt = 0; kt < KT; ++kt) {
        __syncthreads();                       // stage(kt) drained
        if (kt + 1 < KT) { stageA(kt + 1, cur ^ 1); stageB(kt + 1, cur ^ 1); }
#pragma unroll
        for (int ks = 0; ks < 2; ++ks) {
            const int kq = ks * 4 + (lane >> 4);
            short8v bfr[4];
#pragma unroll
            for (int nt = 0; nt < 4; ++nt)
                bfr[nt] = *(const short8v*)
                    &Bsl[cur][kq * 512 + (nt * 16 + (lane & 15)) * 8];
#pragma unroll
            for (int mt = 0; mt < 2; ++mt) {
                short8v afr = *(const short8v*)
                    &Asl[cur][kq * 1024 + (w * 32 + mt * 16 + (lane & 15)) * 8];
#pragma unroll
                for (int nt = 0; nt < 4; ++nt)
                    acc[mt][nt] = __builtin_amdgcn_mfma_f32_16x16x32_bf16(
                        afr, bfr[nt], acc[mt][nt], 0, 0, 0);
            }
        }
        cur ^= 1;
    }
    // epilogue: C frag col=lane&15, row=(lane>>4)*4+r
#pragma unroll
    for (int mt = 0; mt < 2; ++mt)
#pragma unroll
        for (int r = 0; r < 4; ++r) {
            int row = mtile * 128 + w * 32 + mt * 16 + (lane >> 4) * 4 + r;
            long crow = OUT_BT ? ((long)(row & 31) * Tn + (row >> 5)) * N
                               : (long)row * N;
#pragma unroll
            for (int nt = 0; nt < 4; ++nt) {
                int col = ntile * 64 + nt * 16 + (lane & 15);
                float v = acc[mt][nt][r];
                if (BIAS) v += bias[col];
                C[crow + col] = v;
            }
        }
}

// ---------------------------------------------------------------------------
// Phase 2: 32 independent blocks (one per batch b), 512 threads (8 waves).
// W fp8 fragments resident in 128 VGPRs/wave (amdgpu_waves_per_eu(2,2) lifts
// the R7 128-VGPR cap that spilled them). Per stage: fp8 MFMA GEMM from LDS
// A-frags, epilogue -> Sy (wave-local), ew recurrence (fast sigmoid), firing
// -> fp8 into other A_lds buffer + bf16 to F3 in ph3's blocked layout.
// One __syncthreads per stage.
// ---------------------------------------------------------------------------
__global__ void __launch_bounds__(512)
__attribute__((amdgpu_waves_per_eu(2, 2)))
phase2_bpart(
    const unsigned char* __restrict__ Wq,    // [512 n][512 k] fp8
    const float* __restrict__ SYN,
    unsigned short* __restrict__ F3,         // blocked [mtile][kt][kq][row][8]
    const float* __restrict__ tkm, const float* __restrict__ thr,
    const float* __restrict__ aamp, const float* __restrict__ tascr,
    const float* __restrict__ tkasc)
{
    __shared__ unsigned char A_lds[2][32 * 512];  // 2 x 16 KB fp8, swizzled
    __shared__ unsigned short Sy[DELAY][520];     // 20.3 KB bf16

    const int tid = threadIdx.x;
    const int b = blockIdx.x;
    const int lane = tid & 63, w = tid >> 6;

    // zero both A buffers (covers pad rows 20..31 forever)
#pragma unroll
    for (int j = 0; j < 4; ++j)
        *(uint4*)(&A_lds[0][0] + (j * 512 + tid) * 16) = make_uint4(0u,0u,0u,0u);

    // ---- W fragments -> registers (once). B-frag: col n = lane&15,
    // k-chunk = (lane>>4)*8 contiguous fp8 bytes.
    long long wreg[16][4];
#pragma unroll
    for (int kt = 0; kt < 16; ++kt)
#pragma unroll
        for (int nt = 0; nt < 4; ++nt) {
            int n = w * 64 + nt * 16 + (lane & 15);
            int kk = kt * 32 + (lane >> 4) * 8;
            wreg[kt][nt] = *(const long long*)&Wq[(long)n * Hn + kk];
        }

    // ---- per-thread ew params: h = tid (computed once)
    const int h = tid;
    const float dkm  = sigmoidf_(tkm[h]);
    const float th   = thr[h];
    const float am0  = aamp[h],       am1 = aamp[Hn + h];
    const float rr0  = 1.f - 2.f * sigmoidf_(tascr[h]);
    const float rr1  = 1.f - 2.f * sigmoidf_(tascr[Hn + h]);
    const float dk0  = sigmoidf_(tkasc[h]);
    const float dk1  = sigmoidf_(tkasc[Hn + h]);
    const float kR   = dkm * Rc;
    float volt = 0.f, fir = 0.f, a0 = 0.f, a1 = 0.f;

    // F3 per-thread invariants: kt_h = h>>6, kq_h = (h>>3)&7, e_h = h&7
    const long f3_h = ((long)(h >> 6) * 8 + ((h >> 3) & 7)) * 1024 + (h & 7);

    // A-frag byte offsets (row = mt*16 + (lane&15); 8B chunk (lane>>4)*8;
    // XOR swizzle bits 3..5 with row&7)
    const int ar0 = lane & 15, ar1 = 16 + (lane & 15);
    const unsigned a0base = (unsigned)(ar0 * 512 + (lane >> 4) * 8);
    const unsigned a1base = (unsigned)(ar1 * 512 + (lane >> 4) * 8);
    const unsigned swz0 = (unsigned)((ar0 & 7) << 3);
    const unsigned swz1 = (unsigned)((ar1 & 7) << 3);

    __syncthreads();

#pragma unroll 1
    for (int k = 0; k < NBLK; ++k) {
        // issue ff-syn loads first: latency hides under the GEMM
        const float* synk = SYN + (long)k * DELAY * BH + (long)b * Hn + h;
        float ff[DELAY];
#pragma unroll
        for (int s = 0; s < DELAY; ++s)
            ff[s] = synk[(long)s * BH];

        if (k > 0) {
            const unsigned char* Ab = &A_lds[k & 1][0];
            f32x4 acc[2][4] = {};
#pragma unroll
            for (int kt = 0; kt < 16; ++kt) {
                long long afr0 = *(const long long*)(Ab + ((a0base + kt * 32) ^ swz0));
                long long afr1 = *(const long long*)(Ab + ((a1base + kt * 32) ^ swz1));
#pragma unroll
                for (int nt = 0; nt < 4; ++nt) {
                    acc[0][nt] = __builtin_amdgcn_mfma_f32_16x16x32_fp8_fp8(
                        afr0, wreg[kt][nt], acc[0][nt], 0, 0, 0);
                    acc[1][nt] = __builtin_amdgcn_mfma_f32_16x16x32_fp8_fp8(
                        afr1, wreg[kt][nt], acc[1][nt], 0, 0, 0);
                }
            }
            // epilogue -> Sy (own strip, bf16). C frag: col=lane&15,
            // row=(lane>>4)*4+r
#pragma unroll
            for (int mt = 0; mt < 2; ++mt)
#pragma unroll
                for (int r = 0; r < 4; ++r) {
                    int row = mt * 16 + (lane >> 4) * 4 + r;
                    if (row < DELAY) {
#pragma unroll
                        for (int nt = 0; nt < 4; ++nt)
                            Sy[row][w * 64 + nt * 16 + (lane & 15)]
                                = f2bf(acc[mt][nt][r]);
                    }
                }
        }

        // ---- elementwise recurrence (20 steps); Sy strip is wave-local.
        unsigned char* An = &A_lds[(k + 1) & 1][0];
        const int mbase = k * DELAY * Bsz + b;
#pragma unroll
        for (int s = 0; s < DELAY; ++s) {
            float sv = ff[s];
            if (k > 0) sv += bf2f(Sy[s][tid]);
            a0 = a0 * (rr0 * fir * DTc + (1.f - dk0)) + am0 * fir * DTc;
            a1 = a1 * (rr1 * fir * DTc + (1.f - dk1)) + am1 * fir * DTc;
            volt = volt * (1.f - dkm - fir) + kR * (sv + a0 + a1);
            fir = sigfast_(volt - th);
            An[(unsigned)(s * 512 + h) ^ ((unsigned)(s & 7) << 3)] = f2e4m3(fir);
            int m = mbase + s * Bsz;                  // t*32 + b
            // ph3 A-tile stride = KT(8) * 8192 = 65536 elems  (R8 bug: 8192)
            F3[(long)(m >> 7) * 65536 + f3_h + (long)(m & 127) * 8] = f2bf(fir);
        }
        __syncthreads();   // A_lds[(k+1)&1] complete for all waves' next GEMM
    }
}

extern "C" void kernel_launch(void* const* d_in, const int* in_sizes, int n_in,
                              void* d_out, int out_size, void* d_ws, size_t ws_size,
                              hipStream_t stream) {
    const float* input = (const float*)d_in[0];   // [B,T,IN]
    const float* w_iv  = (const float*)d_in[1];   // [IN,H]
    const float* w_lat = (const float*)d_in[2];   // [H,H]
    const float* thr   = (const float*)d_in[3];   // [1,H]
    const float* tkm   = (const float*)d_in[4];   // [1,H]
    const float* aamp  = (const float*)d_in[5];   // [A,1,H]
    const float* tascr = (const float*)d_in[6];   // [A,1,H]
    const float* tkasc = (const float*)d_in[7];   // [A,1,H]
    const float* outw  = (const float*)d_in[8];   // [H,OUT]
    const float* outb  = (const float*)d_in[9];   // [OUT]
    float* out = (float*)d_out;                   // [B,T,OUT]

    const size_t TBH = (size_t)Tn * BH;           // 16,384,000
    float* SYN           = (float*)d_ws;                  // [T][B][H] fp32
    unsigned short* F3   = (unsigned short*)(SYN + TBH);  // blocked bf16 F
    unsigned short* Abf  = F3 + TBH;                      // blocked bf16 input
    unsigned char* Wq    = (unsigned char*)(Abf + (size_t)8192 * 1000);
    unsigned short* Wivb = (unsigned short*)(Wq + (size_t)Hn * Hn);
    unsigned short* Wowb = Wivb + (size_t)INn * Hn;

    // Phase 0: conversions (independent)
    cvt_in<<<1000, 256, 0, stream>>>(input, Abf);
    cvt_b<4, 512><<<64, 256, 0, stream>>>(w_iv, Wivb);    // 8 ntile x 4 kt
    cvt_b<8, 128><<<32, 256, 0, stream>>>(outw, Wowb);    // 2 ntile x 8 kt
    wlat_cvt<<<256, 256, 0, stream>>>(w_lat, Wq);

    // Phase 1: SYN = input @ W_iv  (M=32000, N=512, K=256)
    gemm_mfma<4, false, false><<<dim3(8, 250), 256, 0, stream>>>(
        Abf, Wivb, SYN, nullptr, Hn);

    // Phase 2: 32 independent per-batch blocks, all 50 stages internal
    phase2_bpart<<<32, 512, 0, stream>>>(Wq, SYN, F3,
                                         tkm, thr, aamp, tascr, tkasc);

    // Phase 3: out = F @ out_w + out_b  (M=32000, N=128, K=512)
    gemm_mfma<8, true, true><<<dim3(2, 250), 256, 0, stream>>>(
        F3, Wowb, out, outb, OUTn);
}